// Round 11
// baseline (146.712 us; speedup 1.0000x reference)
//
#include <hip/hip_runtime.h>
#include <cmath>

typedef __attribute__((ext_vector_type(8))) short bf16x8;
typedef __attribute__((ext_vector_type(4))) float f32x4;
typedef __attribute__((ext_vector_type(16))) float f32x16;

#define MFMA16(a,b,c)  __builtin_amdgcn_mfma_f32_16x16x32_bf16((a),(b),(c),0,0,0)
#define MFMA32(a,b,c)  __builtin_amdgcn_mfma_f32_32x32x16_bf16((a),(b),(c),0,0,0)

#if __has_builtin(__builtin_amdgcn_exp2f)
#define EXP2F(x) __builtin_amdgcn_exp2f(x)
#else
#define EXP2F(x) exp2f(x)
#endif

// sqrt(128) * log2(e): folded into w_theta/b_theta at wcvt time.
#define KSCALE 16.3222312f

#define NB 4
#define CH 256
#define CI 128
#define NS 4096   // 64*64 spatial

__device__ __forceinline__ unsigned short f2bf(float f) {
    unsigned int u = __builtin_bit_cast(unsigned int, f);
    u += 0x7fffu + ((u >> 16) & 1u);           // RNE
    return (unsigned short)(u >> 16);
}
__device__ __forceinline__ unsigned int pk2(float lo, float hi) {
    return (unsigned int)f2bf(lo) | ((unsigned int)f2bf(hi) << 16);
}
// truncating pack (softmax P only): 1-op v_perm_b32
__device__ __forceinline__ unsigned int pkt(float lo, float hi) {
    return __builtin_amdgcn_perm(__builtin_bit_cast(unsigned int, hi),
                                 __builtin_bit_cast(unsigned int, lo), 0x07060302u);
}
__device__ __forceinline__ float bf2f(unsigned int ush) {   // low 16 bits
    return __builtin_bit_cast(float, ush << 16);
}

// Half-exchange for P-fragment assembly (verified R3).
__device__ __forceinline__ void plswap(unsigned int& wLow, unsigned int& wHigh) {
    asm volatile("v_permlane32_swap_b32 %0, %1" : "+v"(wLow), "+v"(wHigh));
}

__device__ __forceinline__ f32x16 zero16() {
    f32x16 v;
#pragma unroll
    for (int i = 0; i < 16; i++) v[i] = 0.f;
    return v;
}

// async global->LDS 16B per lane: LDS dest = wave-uniform base + lane*16
__device__ __forceinline__ void gload16(void* lds, const void* g) {
    __builtin_amdgcn_global_load_lds(
        (const __attribute__((address_space(1))) unsigned int*)g,
        (__attribute__((address_space(3))) unsigned int*)lds,
        16, 0, 0);
}

// ---------------------------------------------------------------------------
// Kernel 0: one-time weight convert to bf16, written in MFMA-FRAGMENT ORDER
// (see R9): proj wbf[(wi*2+oh)*16384 + kc*2048 + ot*512 + lane*8 + e],
// outproj wbf[98304 + oh*16384 + kc*4096 + ot*512 + lane*8 + e].
// ---------------------------------------------------------------------------
__global__ void wcvt_kernel(const float* __restrict__ w_g, const float* __restrict__ w_th,
                            const float* __restrict__ w_ph, const float* __restrict__ w_out,
                            const float* __restrict__ b_g, const float* __restrict__ b_th,
                            const float* __restrict__ b_ph,
                            unsigned short* __restrict__ wbf, float* __restrict__ bsc) {
    int i = blockIdx.x * 256 + threadIdx.x;     // 0..131071
    float v;
    if (i < 98304) {
        int wi = i >> 15;             // 0 g, 1 theta, 2 phi
        int r  = i & 32767;
        int oh = r >> 14;
        int r2 = r & 16383;
        int kc = r2 >> 11;            // 0..7
        int r3 = r2 & 2047;
        int ot = r3 >> 9;             // 0..3
        int r4 = r3 & 511;
        int lane = r4 >> 3;           // 0..63
        int e  = r4 & 7;
        int o = oh * 64 + ot * 16 + (lane & 15);
        int c = kc * 32 + (lane >> 4) * 8 + e;
        const float* W = (wi == 0) ? w_g : (wi == 1 ? w_th : w_ph);
        v = W[o * CH + c];
        if (wi == 1) v *= KSCALE;
    } else {
        int r = i - 98304;
        int oh = r >> 14;
        int r2 = r & 16383;
        int kc = r2 >> 12;            // 0..3
        int r3 = r2 & 4095;
        int ot = r3 >> 9;             // 0..7
        int r4 = r3 & 511;
        int lane = r4 >> 3;
        int e = r4 & 7;
        int o = oh * 128 + ot * 16 + (lane & 15);
        int c = kc * 32 + (lane >> 4) * 8 + e;
        v = w_out[o * CI + c];
    }
    wbf[i] = f2bf(v);
    if (i < 128)          bsc[i] = b_g[i];
    else if (i < 256)     bsc[i] = b_th[i - 128] * KSCALE;
    else if (i < 384)     bsc[i] = b_ph[i - 256];
}

// ---------------------------------------------------------------------------
// Kernel 1: FUSED projections.  For theta/phi (wi=1,2) the MFMA operands are
// SWAPPED (A=W, B=x) so D col = s, row = o-local — per lane 4 CONSECUTIVE c
// at fixed s -> packed uint2 stores.  gT (wi=0) keeps original order.
// grid(64 s-tiles of 64, 4 n) = 256 blocks, 512 thr (8 waves).
// ---------------------------------------------------------------------------
__global__ __launch_bounds__(512, 2)
void proj_kernel(const float* __restrict__ x,
                 const unsigned short* __restrict__ wbf, const float* __restrict__ bsc,
                 unsigned short* __restrict__ theta,
                 unsigned short* __restrict__ phi,
                 unsigned short* __restrict__ gT) {
    const int tid  = threadIdx.x;
    const int wid  = tid >> 6;         // 0..7
    const int lane = tid & 63;
    const int quad = lane >> 4;
    const int l15  = lane & 15;
    const int stile = blockIdx.x;      // 0..63
    const int n     = blockIdx.y;
    const int s0    = stile * 64;

    const float* xN = x + (size_t)n * CH * NS;

    __shared__ unsigned int xp[64 * 128];   // 32 KB, swizzled

    // stage: 2048 tasks (128 c-pairs x 16 s-spans of float4), 4/thread
#pragma unroll
    for (int i = 0; i < 4; i++) {
        int t  = i * 512 + tid;
        int s4 = t & 15;
        int cp = t >> 4;                    // 0..127
        const float* p0 = xN + (size_t)(2 * cp) * NS + s0 + s4 * 4;
        float4 a = *(const float4*)p0;
        float4 b = *(const float4*)(p0 + NS);
        int col = (((cp >> 2) ^ (s4 & 7)) << 2) | (cp & 3);   // row>>2 == s4
        unsigned int* xr = xp + (s4 * 4) * 128 + col;
        xr[0]   = pk2(a.x, b.x);
        xr[128] = pk2(a.y, b.y);
        xr[256] = pk2(a.z, b.z);
        xr[384] = pk2(a.w, b.w);
    }
    __syncthreads();

    const int srow = (wid & 3) * 16 + l15;
    const int oh   = wid >> 2;              // o-half
    const int sw7  = (srow >> 2) & 7;
#pragma unroll
    for (int wi = 0; wi < 3; wi++) {
        f32x4 acc[4];
#pragma unroll
        for (int ot = 0; ot < 4; ot++) acc[ot] = (f32x4){0.f, 0.f, 0.f, 0.f};
        const unsigned short* W = wbf + (size_t)(wi * 2 + oh) * 16384;
#pragma unroll
        for (int kc = 0; kc < 8; kc++) {
            bf16x8 af = *(const bf16x8*)(&xp[srow * 128 + (((kc * 4 + quad) ^ sw7) << 2)]);
#pragma unroll
            for (int ot = 0; ot < 4; ot++) {
                bf16x8 wf = *(const bf16x8*)(W + kc * 2048 + ot * 512 + lane * 8);
                if (wi == 0) acc[ot] = MFMA16(af, wf, acc[ot]);   // D: col=o, row=s
                else         acc[ot] = MFMA16(wf, af, acc[ot]);   // D: col=s, row=o
            }
        }
        const float* Bv = bsc + wi * 128 + oh * 64;
        if (wi == 0) {
#pragma unroll
            for (int ot = 0; ot < 4; ot++) {
                int o = oh * 64 + ot * 16 + l15;
                float bias = Bv[ot * 16 + l15];
                // gT[c][s]: r=0..3 are consecutive s -> pack uint2 (4 bf16)
                int sg0 = s0 + (wid & 3) * 16 + quad * 4;
                uint2 w;
                w.x = pk2(acc[ot][0] + bias, acc[ot][1] + bias);
                w.y = pk2(acc[ot][2] + bias, acc[ot][3] + bias);
                *(uint2*)(gT + (size_t)((size_t)n * CI + o) * NS + sg0) = w;
            }
        } else {
            unsigned short* dst = (wi == 1) ? theta : phi;
            const int sgl = s0 + srow;           // global s for this lane
#pragma unroll
            for (int ot = 0; ot < 4; ot++) {
                f32x4 bb = *(const f32x4*)(Bv + ot * 16 + quad * 4);
                uint2 w;
                w.x = pk2(acc[ot][0] + bb[0], acc[ot][1] + bb[1]);
                w.y = pk2(acc[ot][2] + bb[2], acc[ot][3] + bb[3]);
                *(uint2*)(dst + ((size_t)n * NS + sgl) * CI + oh * 64 + ot * 16 + quad * 4) = w;
            }
        }
    }
}

// ---------------------------------------------------------------------------
// Kernel 2: flash attention partials — R3-exact structure (measured 43-45us).
// 256 thr (4 waves), q=32/wave, 64-s chunks, K/V double-buffer, 64 KB LDS,
// split=4.  grid(16 = split*4+n, 32 qb) = 512 blocks.
// ---------------------------------------------------------------------------
__global__ __launch_bounds__(256, 2)
void attn_kernel(const unsigned short* __restrict__ theta,
                 const unsigned short* __restrict__ phi,
                 const unsigned short* __restrict__ gT,
                 unsigned short* __restrict__ Opart,
                 float* __restrict__ lbuf) {
    const int tid  = threadIdx.x;
    const int wid  = tid >> 6;          // 0..3
    const int lane = tid & 63;
    const int l31  = lane & 31;
    const int lh32 = lane >> 5;         // 0..1
    const int sn    = blockIdx.x;       // 0..15
    const int split = sn >> 2;          // 0..3
    const int n     = sn & 3;
    const int qb    = blockIdx.y;       // 0..31
    const int qbase = qb * 128 + wid * 32;

    const unsigned short* thN = theta + (size_t)n * NS * CI;
    const unsigned short* phN = phi   + (size_t)n * NS * CI;
    const unsigned short* gN  = gT    + (size_t)n * CI * NS;

    // K dbuf: 2 x [64 s][128 c] (slot ^ (s&15))   32 KB
    // V dbuf: 2 x [128 c][64 s] (slot ^ (c&7))    32 KB     total 64 KB
    __shared__ unsigned short smem[32768];
    unsigned short* Kb = smem;              // + cur*8192
    unsigned short* Vb = smem + 16384;      // + cur*8192

    // Q B-fragments: col = q = l31, k = lh32*8 + e within each 16-c slice
    bf16x8 qf[8];
#pragma unroll
    for (int kc = 0; kc < 8; kc++)
        qf[kc] = *(const bf16x8*)(thN + (size_t)(qbase + l31) * CI + kc * 16 + lh32 * 8);

    f32x16 O[4];    // O^T tiles: row c = ct*32 + (reg&3)+8*(reg>>2)+4*lh32, col q = l31
#pragma unroll
    for (int ct = 0; ct < 4; ct++) O[ct] = zero16();
    float lrun = 0.f;

    const int sbase0 = split * 1024;
    const int lh16 = lane >> 4, lm16 = lane & 15;
    const int lh8  = lane >> 3, lm8  = lane & 7;

    // stage chunk 0 -> buffer 0 (4 K segs + 4 V segs per wave)
#pragma unroll
    for (int i = 0; i < 4; i++) {
        int seg = wid * 4 + i;                  // 0..15
        int s   = seg * 4 + lh16;               // 0..63
        int j   = lm16 ^ (s & 15);
        gload16(Kb + seg * 512, phN + (size_t)(sbase0 + s) * CI + j * 8);
    }
#pragma unroll
    for (int i = 0; i < 4; i++) {
        int seg = wid * 4 + i;
        int c   = seg * 8 + lh8;                // 0..127
        int j   = lm8 ^ (c & 7);
        gload16(Vb + seg * 512, gN + (size_t)c * NS + sbase0 + j * 8);
    }

    for (int ck = 0; ck < 16; ck++) {
        const int cur = ck & 1, nxt = cur ^ 1;
        unsigned short* Kc = Kb + cur * 8192;
        unsigned short* Vc = Vb + cur * 8192;
        __syncthreads();    // drains cur loads; prev compute done

        if (ck + 1 < 16) {  // async prefetch next chunk
            const int sb1 = sbase0 + (ck + 1) * 64;
#pragma unroll
            for (int i = 0; i < 4; i++) {
                int seg = wid * 4 + i;
                int s   = seg * 4 + lh16;
                int j   = lm16 ^ (s & 15);
                gload16(Kb + nxt * 8192 + seg * 512, phN + (size_t)(sb1 + s) * CI + j * 8);
            }
#pragma unroll
            for (int i = 0; i < 4; i++) {
                int seg = wid * 4 + i;
                int c   = seg * 8 + lh8;
                int j   = lm8 ^ (c & 7);
                gload16(Vb + nxt * 8192 + seg * 512, gN + (size_t)c * NS + sb1 + j * 8);
            }
        }

        // QK^T -> S^T: 2 s-blocks x 8 c-slices
        f32x16 S[2];
        S[0] = zero16(); S[1] = zero16();
        __builtin_amdgcn_s_setprio(1);
#pragma unroll
        for (int sb = 0; sb < 2; sb++) {
#pragma unroll
            for (int kc = 0; kc < 8; kc++) {
                int s = sb * 32 + l31;
                bf16x8 kf = *(const bf16x8*)(Kc + s * 128 + (((kc * 2 + lh32) ^ (s & 15)) * 8));
                S[sb] = MFMA32(kf, qf[kc], S[sb]);
            }
        }
        __builtin_amdgcn_s_setprio(0);

        // softmax: p = exp2(S); assemble P B-fragments (k=s) per 16-s slice.
        bf16x8 pf[4];
        float lsum = 0.f;
#pragma unroll
        for (int ks = 0; ks < 4; ks++) {
            const int sb = ks >> 1, b = ks & 1;
            float pA[4], pB[4];
#pragma unroll
            for (int m = 0; m < 4; m++) {
                pA[m] = EXP2F(S[sb][(2 * b) * 4 + m]);       // even g: s16 = m+4h
                pB[m] = EXP2F(S[sb][(2 * b + 1) * 4 + m]);   // odd g:  s16 = 8+m+4h
            }
            lsum += ((pA[0] + pA[1]) + (pA[2] + pA[3]))
                  + ((pB[0] + pB[1]) + (pB[2] + pB[3]));
            unsigned int wA0 = pkt(pA[0], pA[1]);
            unsigned int wA1 = pkt(pA[2], pA[3]);
            unsigned int wB0 = pkt(pB[0], pB[1]);
            unsigned int wB1 = pkt(pB[2], pB[3]);
            plswap(wA0, wB0);   // wA0 -> u0, wB0 -> u2
            plswap(wA1, wB1);   // wA1 -> u1, wB1 -> u3
            union { unsigned int u[4]; bf16x8 v; } P;
            P.u[0] = wA0; P.u[1] = wA1; P.u[2] = wB0; P.u[3] = wB1;
            pf[ks] = P.v;
        }
        lrun += lsum;

        // PV: O^T += V^T . P^T over 4 K=16 slices (P from registers).
        __builtin_amdgcn_s_setprio(1);
#pragma unroll
        for (int ks = 0; ks < 4; ks++) {
#pragma unroll
            for (int ct = 0; ct < 4; ct++) {
                int c = ct * 32 + l31;
                bf16x8 vf = *(const bf16x8*)(Vc + c * 64 + (((ks * 2 + lh32) ^ (c & 7)) * 8));
                O[ct] = MFMA32(vf, pf[ks], O[ct]);
            }
        }
        __builtin_amdgcn_s_setprio(0);
    }

    // epilogue: O^T (32x32 tiles) -> Opart[q][c] bf16 via per-wave LDS
    // transpose, 2 passes of 2 ct (8 KB tb per wave), XOR-swizzled 16B slots.
    __syncthreads();
    float* tb = (float*)smem + wid * 2048;   // 4 waves x 8 KB
    const size_t obase = ((size_t)(split * NB + n)) * NS * CI;
#pragma unroll
    for (int pass = 0; pass < 2; pass++) {
#pragma unroll
        for (int cti = 0; cti < 2; cti++) {
            const int ct = pass * 2 + cti;
#pragma unroll
            for (int g = 0; g < 4; g++) {
                const int c_local = cti * 32 + 8 * g + 4 * lh32;   // +0..3
                const int slot = (c_local >> 2) ^ (l31 & 15);
                f32x4 v;
                v[0] = O[ct][4 * g + 0]; v[1] = O[ct][4 * g + 1];
                v[2] = O[ct][4 * g + 2]; v[3] = O[ct][4 * g + 3];
                *(f32x4*)(tb + l31 * 64 + slot * 4) = v;
            }
        }
#pragma unroll
        for (int i = 0; i < 8; i++) {
            const int qr  = i * 4 + (lane >> 4);    // 0..31
            const int lin = lane & 15;
            f32x4 v = *(const f32x4*)(tb + qr * 64 + ((lin ^ (qr & 15)) * 4));
            uint2 w;
            w.x = pk2(v[0], v[1]);
            w.y = pk2(v[2], v[3]);
            *(uint2*)(Opart + obase + (size_t)(qbase + qr) * CI + pass * 64 + lin * 4) = w;
        }
    }
    lrun += __shfl_xor(lrun, 32);
    if (lane < 32)
        lbuf[(split * NB + n) * NS + qbase + l31] = lrun;
}

// ---------------------------------------------------------------------------
// Kernel 3: fused merge (4 bf16 partials) + output projection + residual.
// Opart STAGED INTO LDS via coalesced global_load_lds with pre-swizzled
// source chunks (attn's K-staging pattern).  R10 bug fixed: LDS seg stride
// is 512 shorts (1 KB per gload16 = 4 rows x 256 B), not 2048.
// LDS 64 KB (4 k-tiles x [64 s][128 c], chunk g stored at pos g^(s&15)).
// grid(64 s-tiles, 2 o-halves, 4 n) = 512 blocks, 256 thr, 2 blocks/CU.
// ---------------------------------------------------------------------------
__global__ __launch_bounds__(256, 2)
void outproj_kernel(const float* __restrict__ x,
                    const unsigned short* __restrict__ wbf,
                    const float* __restrict__ b_out,
                    const unsigned short* __restrict__ Opart,
                    const float* __restrict__ lbuf,
                    float* __restrict__ out) {
    const int tid  = threadIdx.x;
    const int wid  = tid >> 6;
    const int lane = tid & 63;
    const int quad = lane >> 4;
    const int l15  = lane & 15;
    const int oh = blockIdx.y;
    const int n  = blockIdx.z;
    const int s0 = blockIdx.x * 64;
    const int sw = s0 + wid * 16;
    const int T  = NB * NS;

    __shared__ unsigned short Ob[4 * 64 * 128];   // 64 KB

    // stage 4 partial tiles [64 s][128 c] with pre-swizzled source chunks.
    // One gload16 = 1 KB = 4 rows of 256 B -> seg stride 512 shorts.
    const int lh16 = lane >> 4, lm16 = lane & 15;
#pragma unroll
    for (int k = 0; k < 4; k++) {
#pragma unroll
        for (int i = 0; i < 4; i++) {
            int seg = wid * 4 + i;              // 0..15 (4 rows each)
            int s   = seg * 4 + lh16;           // 0..63
            int j   = lm16 ^ (s & 15);          // swizzled 16B chunk
            gload16(Ob + k * 8192 + seg * 512,
                    Opart + ((size_t)k * T + (size_t)n * NS + s0 + s) * CI + j * 8);
        }
    }

    const int srow = n * NS + sw + l15;
    float l = 0.f;
#pragma unroll
    for (int k = 0; k < 4; k++) l += lbuf[k * T + srow];
    float rinv = 1.0f / l;

    __syncthreads();   // drains all gload16

    // merge from LDS: lane's row sL = wid*16 + l15, chunk g = kc*4+quad at
    // slot g ^ (sL&15)
    const int sL = wid * 16 + l15;
    bf16x8 yb[4];
#pragma unroll
    for (int kc = 0; kc < 4; kc++) {
        float f0 = 0.f, f1 = 0.f, f2 = 0.f, f3 = 0.f;
        float f4 = 0.f, f5 = 0.f, f6 = 0.f, f7 = 0.f;
        const int slot = (kc * 4 + quad) ^ (sL & 15);
#pragma unroll
        for (int k = 0; k < 4; k++) {
            uint4 v = *(const uint4*)(Ob + k * 8192 + sL * 128 + slot * 8);
            f0 += bf2f(v.x & 0xffffu); f1 += bf2f(v.x >> 16);
            f2 += bf2f(v.y & 0xffffu); f3 += bf2f(v.y >> 16);
            f4 += bf2f(v.z & 0xffffu); f5 += bf2f(v.z >> 16);
            f6 += bf2f(v.w & 0xffffu); f7 += bf2f(v.w >> 16);
        }
        union { unsigned int uu[4]; bf16x8 vv; } r;
        r.uu[0] = pk2(f0 * rinv, f1 * rinv);
        r.uu[1] = pk2(f2 * rinv, f3 * rinv);
        r.uu[2] = pk2(f4 * rinv, f5 * rinv);
        r.uu[3] = pk2(f6 * rinv, f7 * rinv);
        yb[kc] = r.vv;
    }

    const unsigned short* wof = wbf + 98304 + (size_t)oh * 16384;
    f32x4 acc[8];
#pragma unroll
    for (int ot = 0; ot < 8; ot++) acc[ot] = (f32x4){0.f, 0.f, 0.f, 0.f};
#pragma unroll
    for (int kc = 0; kc < 4; kc++) {
#pragma unroll
        for (int ot = 0; ot < 8; ot++) {
            bf16x8 wa = *(const bf16x8*)(wof + kc * 4096 + ot * 512 + lane * 8);
            acc[ot] = MFMA16(wa, yb[kc], acc[ot]);
        }
    }
#pragma unroll
    for (int ot = 0; ot < 8; ot++) {
#pragma unroll
        for (int r = 0; r < 4; r++) {
            int o = oh * 128 + ot * 16 + quad * 4 + r;
            size_t idx = ((size_t)n * CH + o) * NS + sw + l15;
            out[idx] = x[idx] + acc[ot][r] + b_out[o];
        }
    }
}

// ---------------------------------------------------------------------------
extern "C" void kernel_launch(void* const* d_in, const int* in_sizes, int n_in,
                              void* d_out, int out_size, void* d_ws, size_t ws_size,
                              hipStream_t stream) {
    const float* x     = (const float*)d_in[0];
    const float* w_g   = (const float*)d_in[1];
    const float* b_g   = (const float*)d_in[2];
    const float* w_th  = (const float*)d_in[3];
    const float* b_th  = (const float*)d_in[4];
    const float* w_ph  = (const float*)d_in[5];
    const float* b_ph  = (const float*)d_in[6];
    const float* w_out = (const float*)d_in[7];
    const float* b_out = (const float*)d_in[8];
    float* out = (float*)d_out;

    char* ws = (char*)d_ws;
    unsigned short* theta = (unsigned short*)(ws + 0);          //  4 MiB
    unsigned short* phi   = (unsigned short*)(ws + 4194304);    //  4 MiB
    unsigned short* gT    = (unsigned short*)(ws + 8388608);    //  4 MiB
    unsigned short* Opart = (unsigned short*)(ws + 12582912);   // 16 MiB (4 splits bf16)
    float* lbuf  = (float*)(ws + 29360128);                     // 256 KiB
    unsigned short* wbf = (unsigned short*)(ws + 29622272);     // 256 KiB
    float* bsc   = (float*)(ws + 29884416);                     //  1.5 KiB

    wcvt_kernel<<<512, 256, 0, stream>>>(w_g, w_th, w_ph, w_out, b_g, b_th, b_ph, wbf, bsc);
    proj_kernel<<<dim3(64, NB), 512, 0, stream>>>(x, wbf, bsc, theta, phi, gT);
    attn_kernel<<<dim3(16, 32), 256, 0, stream>>>(theta, phi, gT, Opart, lbuf);
    outproj_kernel<<<dim3(64, 2, NB), 256, 0, stream>>>(x, wbf, b_out, Opart, lbuf, out);
}

// Round 12
// 143.087 us; speedup vs baseline: 1.0253x; 1.0253x over previous
//
#include <hip/hip_runtime.h>
#include <cmath>

typedef __attribute__((ext_vector_type(8))) short bf16x8;
typedef __attribute__((ext_vector_type(4))) float f32x4;
typedef __attribute__((ext_vector_type(16))) float f32x16;

#define MFMA16(a,b,c)  __builtin_amdgcn_mfma_f32_16x16x32_bf16((a),(b),(c),0,0,0)
#define MFMA32(a,b,c)  __builtin_amdgcn_mfma_f32_32x32x16_bf16((a),(b),(c),0,0,0)

#if __has_builtin(__builtin_amdgcn_exp2f)
#define EXP2F(x) __builtin_amdgcn_exp2f(x)
#else
#define EXP2F(x) exp2f(x)
#endif

// sqrt(128) * log2(e): folded into w_theta/b_theta at wcvt time.
#define KSCALE 16.3222312f

#define NB 4
#define CH 256
#define CI 128
#define NS 4096   // 64*64 spatial

__device__ __forceinline__ unsigned short f2bf(float f) {
    unsigned int u = __builtin_bit_cast(unsigned int, f);
    u += 0x7fffu + ((u >> 16) & 1u);           // RNE
    return (unsigned short)(u >> 16);
}
__device__ __forceinline__ unsigned int pk2(float lo, float hi) {
    return (unsigned int)f2bf(lo) | ((unsigned int)f2bf(hi) << 16);
}
// truncating pack (softmax P only): 1-op v_perm_b32
__device__ __forceinline__ unsigned int pkt(float lo, float hi) {
    return __builtin_amdgcn_perm(__builtin_bit_cast(unsigned int, hi),
                                 __builtin_bit_cast(unsigned int, lo), 0x07060302u);
}
__device__ __forceinline__ float bf2f(unsigned int ush) {   // low 16 bits
    return __builtin_bit_cast(float, ush << 16);
}

// Half-exchange for P-fragment assembly (verified R3).
__device__ __forceinline__ void plswap(unsigned int& wLow, unsigned int& wHigh) {
    asm volatile("v_permlane32_swap_b32 %0, %1" : "+v"(wLow), "+v"(wHigh));
}

__device__ __forceinline__ f32x16 zero16() {
    f32x16 v;
#pragma unroll
    for (int i = 0; i < 16; i++) v[i] = 0.f;
    return v;
}

// async global->LDS 16B per lane: LDS dest = wave-uniform base + lane*16
__device__ __forceinline__ void gload16(void* lds, const void* g) {
    __builtin_amdgcn_global_load_lds(
        (const __attribute__((address_space(1))) unsigned int*)g,
        (__attribute__((address_space(3))) unsigned int*)lds,
        16, 0, 0);
}

// ---------------------------------------------------------------------------
// Kernel 0: one-time weight convert to bf16, written in MFMA-FRAGMENT ORDER
// (see R9): proj wbf[(wi*2+oh)*16384 + kc*2048 + ot*512 + lane*8 + e],
// outproj wbf[98304 + oh*16384 + kc*4096 + ot*512 + lane*8 + e].
// ---------------------------------------------------------------------------
__global__ void wcvt_kernel(const float* __restrict__ w_g, const float* __restrict__ w_th,
                            const float* __restrict__ w_ph, const float* __restrict__ w_out,
                            const float* __restrict__ b_g, const float* __restrict__ b_th,
                            const float* __restrict__ b_ph,
                            unsigned short* __restrict__ wbf, float* __restrict__ bsc) {
    int i = blockIdx.x * 256 + threadIdx.x;     // 0..131071
    float v;
    if (i < 98304) {
        int wi = i >> 15;             // 0 g, 1 theta, 2 phi
        int r  = i & 32767;
        int oh = r >> 14;
        int r2 = r & 16383;
        int kc = r2 >> 11;            // 0..7
        int r3 = r2 & 2047;
        int ot = r3 >> 9;             // 0..3
        int r4 = r3 & 511;
        int lane = r4 >> 3;           // 0..63
        int e  = r4 & 7;
        int o = oh * 64 + ot * 16 + (lane & 15);
        int c = kc * 32 + (lane >> 4) * 8 + e;
        const float* W = (wi == 0) ? w_g : (wi == 1 ? w_th : w_ph);
        v = W[o * CH + c];
        if (wi == 1) v *= KSCALE;
    } else {
        int r = i - 98304;
        int oh = r >> 14;
        int r2 = r & 16383;
        int kc = r2 >> 12;            // 0..3
        int r3 = r2 & 4095;
        int ot = r3 >> 9;             // 0..7
        int r4 = r3 & 511;
        int lane = r4 >> 3;
        int e = r4 & 7;
        int o = oh * 128 + ot * 16 + (lane & 15);
        int c = kc * 32 + (lane >> 4) * 8 + e;
        v = w_out[o * CI + c];
    }
    wbf[i] = f2bf(v);
    if (i < 128)          bsc[i] = b_g[i];
    else if (i < 256)     bsc[i] = b_th[i - 128] * KSCALE;
    else if (i < 384)     bsc[i] = b_ph[i - 256];
}

// ---------------------------------------------------------------------------
// Kernel 1: FUSED projections.  NEW (R12): 1024 threads (16 waves) per
// block, 1 block/CU -> 16 waves/CU (was 8) for latency hiding, same single
// x staging (no extra traffic).  Waves: squad = wid&3 (s-quarter, 16 rows),
// oq = wid>>2 (o-quarter): oh = oq>>1, ot pair = (oq&1)*2 + {0,1}.
// theta/phi use swapped operands (D col=s) -> packed uint2 stores.
// grid(64 s-tiles, 4 n) = 256 blocks.
// ---------------------------------------------------------------------------
__global__ __launch_bounds__(1024, 4)
void proj_kernel(const float* __restrict__ x,
                 const unsigned short* __restrict__ wbf, const float* __restrict__ bsc,
                 unsigned short* __restrict__ theta,
                 unsigned short* __restrict__ phi,
                 unsigned short* __restrict__ gT) {
    const int tid  = threadIdx.x;
    const int wid  = tid >> 6;         // 0..15
    const int lane = tid & 63;
    const int quad = lane >> 4;
    const int l15  = lane & 15;
    const int stile = blockIdx.x;      // 0..63
    const int n     = blockIdx.y;
    const int s0    = stile * 64;

    const float* xN = x + (size_t)n * CH * NS;

    __shared__ unsigned int xp[64 * 128];   // 32 KB, swizzled

    // stage: 2048 tasks (128 c-pairs x 16 s-spans of float4), 2/thread
#pragma unroll
    for (int i = 0; i < 2; i++) {
        int t  = i * 1024 + tid;
        int s4 = t & 15;
        int cp = t >> 4;                    // 0..127
        const float* p0 = xN + (size_t)(2 * cp) * NS + s0 + s4 * 4;
        float4 a = *(const float4*)p0;
        float4 b = *(const float4*)(p0 + NS);
        int col = (((cp >> 2) ^ (s4 & 7)) << 2) | (cp & 3);   // row>>2 == s4
        unsigned int* xr = xp + (s4 * 4) * 128 + col;
        xr[0]   = pk2(a.x, b.x);
        xr[128] = pk2(a.y, b.y);
        xr[256] = pk2(a.z, b.z);
        xr[384] = pk2(a.w, b.w);
    }
    __syncthreads();

    const int squad = wid & 3;
    const int oq    = wid >> 2;             // 0..3
    const int oh    = oq >> 1;
    const int otp   = (oq & 1) * 2;
    const int srow  = squad * 16 + l15;
    const int sw7   = (srow >> 2) & 7;
#pragma unroll
    for (int wi = 0; wi < 3; wi++) {
        f32x4 acc[2];
        acc[0] = (f32x4){0.f, 0.f, 0.f, 0.f};
        acc[1] = (f32x4){0.f, 0.f, 0.f, 0.f};
        const unsigned short* W = wbf + (size_t)(wi * 2 + oh) * 16384;
#pragma unroll
        for (int kc = 0; kc < 8; kc++) {
            bf16x8 af = *(const bf16x8*)(&xp[srow * 128 + (((kc * 4 + quad) ^ sw7) << 2)]);
#pragma unroll
            for (int oi = 0; oi < 2; oi++) {
                int ot = otp + oi;
                bf16x8 wf = *(const bf16x8*)(W + kc * 2048 + ot * 512 + lane * 8);
                if (wi == 0) acc[oi] = MFMA16(af, wf, acc[oi]);   // D: col=o, row=s
                else         acc[oi] = MFMA16(wf, af, acc[oi]);   // D: col=s, row=o
            }
        }
        const float* Bv = bsc + wi * 128 + oh * 64;
        if (wi == 0) {
#pragma unroll
            for (int oi = 0; oi < 2; oi++) {
                int ot = otp + oi;
                int o = oh * 64 + ot * 16 + l15;
                float bias = Bv[ot * 16 + l15];
                int sg0 = s0 + squad * 16 + quad * 4;
                uint2 w;
                w.x = pk2(acc[oi][0] + bias, acc[oi][1] + bias);
                w.y = pk2(acc[oi][2] + bias, acc[oi][3] + bias);
                *(uint2*)(gT + (size_t)((size_t)n * CI + o) * NS + sg0) = w;
            }
        } else {
            unsigned short* dst = (wi == 1) ? theta : phi;
            const int sgl = s0 + srow;           // global s for this lane
#pragma unroll
            for (int oi = 0; oi < 2; oi++) {
                int ot = otp + oi;
                f32x4 bb = *(const f32x4*)(Bv + ot * 16 + quad * 4);
                uint2 w;
                w.x = pk2(acc[oi][0] + bb[0], acc[oi][1] + bb[1]);
                w.y = pk2(acc[oi][2] + bb[2], acc[oi][3] + bb[3]);
                *(uint2*)(dst + ((size_t)n * NS + sgl) * CI + oh * 64 + ot * 16 + quad * 4) = w;
            }
        }
    }
}

// ---------------------------------------------------------------------------
// Kernel 2: flash attention partials — R3-exact structure (measured 43-45us).
// 256 thr (4 waves), q=32/wave, 64-s chunks, K/V double-buffer, 64 KB LDS,
// split=4.  grid(16 = split*4+n, 32 qb) = 512 blocks.
// ---------------------------------------------------------------------------
__global__ __launch_bounds__(256, 2)
void attn_kernel(const unsigned short* __restrict__ theta,
                 const unsigned short* __restrict__ phi,
                 const unsigned short* __restrict__ gT,
                 unsigned short* __restrict__ Opart,
                 float* __restrict__ lbuf) {
    const int tid  = threadIdx.x;
    const int wid  = tid >> 6;          // 0..3
    const int lane = tid & 63;
    const int l31  = lane & 31;
    const int lh32 = lane >> 5;         // 0..1
    const int sn    = blockIdx.x;       // 0..15
    const int split = sn >> 2;          // 0..3
    const int n     = sn & 3;
    const int qb    = blockIdx.y;       // 0..31
    const int qbase = qb * 128 + wid * 32;

    const unsigned short* thN = theta + (size_t)n * NS * CI;
    const unsigned short* phN = phi   + (size_t)n * NS * CI;
    const unsigned short* gN  = gT    + (size_t)n * CI * NS;

    // K dbuf: 2 x [64 s][128 c] (slot ^ (s&15))   32 KB
    // V dbuf: 2 x [128 c][64 s] (slot ^ (c&7))    32 KB     total 64 KB
    __shared__ unsigned short smem[32768];
    unsigned short* Kb = smem;              // + cur*8192
    unsigned short* Vb = smem + 16384;      // + cur*8192

    // Q B-fragments: col = q = l31, k = lh32*8 + e within each 16-c slice
    bf16x8 qf[8];
#pragma unroll
    for (int kc = 0; kc < 8; kc++)
        qf[kc] = *(const bf16x8*)(thN + (size_t)(qbase + l31) * CI + kc * 16 + lh32 * 8);

    f32x16 O[4];    // O^T tiles: row c = ct*32 + (reg&3)+8*(reg>>2)+4*lh32, col q = l31
#pragma unroll
    for (int ct = 0; ct < 4; ct++) O[ct] = zero16();
    float lrun = 0.f;

    const int sbase0 = split * 1024;
    const int lh16 = lane >> 4, lm16 = lane & 15;
    const int lh8  = lane >> 3, lm8  = lane & 7;

    // stage chunk 0 -> buffer 0 (4 K segs + 4 V segs per wave)
#pragma unroll
    for (int i = 0; i < 4; i++) {
        int seg = wid * 4 + i;                  // 0..15
        int s   = seg * 4 + lh16;               // 0..63
        int j   = lm16 ^ (s & 15);
        gload16(Kb + seg * 512, phN + (size_t)(sbase0 + s) * CI + j * 8);
    }
#pragma unroll
    for (int i = 0; i < 4; i++) {
        int seg = wid * 4 + i;
        int c   = seg * 8 + lh8;                // 0..127
        int j   = lm8 ^ (c & 7);
        gload16(Vb + seg * 512, gN + (size_t)c * NS + sbase0 + j * 8);
    }

    for (int ck = 0; ck < 16; ck++) {
        const int cur = ck & 1, nxt = cur ^ 1;
        unsigned short* Kc = Kb + cur * 8192;
        unsigned short* Vc = Vb + cur * 8192;
        __syncthreads();    // drains cur loads; prev compute done

        if (ck + 1 < 16) {  // async prefetch next chunk
            const int sb1 = sbase0 + (ck + 1) * 64;
#pragma unroll
            for (int i = 0; i < 4; i++) {
                int seg = wid * 4 + i;
                int s   = seg * 4 + lh16;
                int j   = lm16 ^ (s & 15);
                gload16(Kb + nxt * 8192 + seg * 512, phN + (size_t)(sb1 + s) * CI + j * 8);
            }
#pragma unroll
            for (int i = 0; i < 4; i++) {
                int seg = wid * 4 + i;
                int c   = seg * 8 + lh8;
                int j   = lm8 ^ (c & 7);
                gload16(Vb + nxt * 8192 + seg * 512, gN + (size_t)c * NS + sb1 + j * 8);
            }
        }

        // QK^T -> S^T: 2 s-blocks x 8 c-slices
        f32x16 S[2];
        S[0] = zero16(); S[1] = zero16();
        __builtin_amdgcn_s_setprio(1);
#pragma unroll
        for (int sb = 0; sb < 2; sb++) {
#pragma unroll
            for (int kc = 0; kc < 8; kc++) {
                int s = sb * 32 + l31;
                bf16x8 kf = *(const bf16x8*)(Kc + s * 128 + (((kc * 2 + lh32) ^ (s & 15)) * 8));
                S[sb] = MFMA32(kf, qf[kc], S[sb]);
            }
        }
        __builtin_amdgcn_s_setprio(0);

        // softmax: p = exp2(S); assemble P B-fragments (k=s) per 16-s slice.
        bf16x8 pf[4];
        float lsum = 0.f;
#pragma unroll
        for (int ks = 0; ks < 4; ks++) {
            const int sb = ks >> 1, b = ks & 1;
            float pA[4], pB[4];
#pragma unroll
            for (int m = 0; m < 4; m++) {
                pA[m] = EXP2F(S[sb][(2 * b) * 4 + m]);       // even g: s16 = m+4h
                pB[m] = EXP2F(S[sb][(2 * b + 1) * 4 + m]);   // odd g:  s16 = 8+m+4h
            }
            lsum += ((pA[0] + pA[1]) + (pA[2] + pA[3]))
                  + ((pB[0] + pB[1]) + (pB[2] + pB[3]));
            unsigned int wA0 = pkt(pA[0], pA[1]);
            unsigned int wA1 = pkt(pA[2], pA[3]);
            unsigned int wB0 = pkt(pB[0], pB[1]);
            unsigned int wB1 = pkt(pB[2], pB[3]);
            plswap(wA0, wB0);   // wA0 -> u0, wB0 -> u2
            plswap(wA1, wB1);   // wA1 -> u1, wB1 -> u3
            union { unsigned int u[4]; bf16x8 v; } P;
            P.u[0] = wA0; P.u[1] = wA1; P.u[2] = wB0; P.u[3] = wB1;
            pf[ks] = P.v;
        }
        lrun += lsum;

        // PV: O^T += V^T . P^T over 4 K=16 slices (P from registers).
        __builtin_amdgcn_s_setprio(1);
#pragma unroll
        for (int ks = 0; ks < 4; ks++) {
#pragma unroll
            for (int ct = 0; ct < 4; ct++) {
                int c = ct * 32 + l31;
                bf16x8 vf = *(const bf16x8*)(Vc + c * 64 + (((ks * 2 + lh32) ^ (c & 7)) * 8));
                O[ct] = MFMA32(vf, pf[ks], O[ct]);
            }
        }
        __builtin_amdgcn_s_setprio(0);
    }

    // epilogue: O^T (32x32 tiles) -> Opart[q][c] bf16 via per-wave LDS
    // transpose, 2 passes of 2 ct (8 KB tb per wave), XOR-swizzled 16B slots.
    __syncthreads();
    float* tb = (float*)smem + wid * 2048;   // 4 waves x 8 KB
    const size_t obase = ((size_t)(split * NB + n)) * NS * CI;
#pragma unroll
    for (int pass = 0; pass < 2; pass++) {
#pragma unroll
        for (int cti = 0; cti < 2; cti++) {
            const int ct = pass * 2 + cti;
#pragma unroll
            for (int g = 0; g < 4; g++) {
                const int c_local = cti * 32 + 8 * g + 4 * lh32;   // +0..3
                const int slot = (c_local >> 2) ^ (l31 & 15);
                f32x4 v;
                v[0] = O[ct][4 * g + 0]; v[1] = O[ct][4 * g + 1];
                v[2] = O[ct][4 * g + 2]; v[3] = O[ct][4 * g + 3];
                *(f32x4*)(tb + l31 * 64 + slot * 4) = v;
            }
        }
#pragma unroll
        for (int i = 0; i < 8; i++) {
            const int qr  = i * 4 + (lane >> 4);    // 0..31
            const int lin = lane & 15;
            f32x4 v = *(const f32x4*)(tb + qr * 64 + ((lin ^ (qr & 15)) * 4));
            uint2 w;
            w.x = pk2(v[0], v[1]);
            w.y = pk2(v[2], v[3]);
            *(uint2*)(Opart + obase + (size_t)(qbase + qr) * CI + pass * 64 + lin * 4) = w;
        }
    }
    lrun += __shfl_xor(lrun, 32);
    if (lane < 32)
        lbuf[(split * NB + n) * NS + qbase + l31] = lrun;
}

// ---------------------------------------------------------------------------
// Kernel 3: fused merge (4 bf16 partials) + output projection + residual.
// NEW (R12): 512 threads (8 waves), 2 blocks/CU -> 16 waves/CU (was 8).
// Waves: swq = wid&3 (s-quarter), oth = wid>>2 (o-half of the 8 ot).
// Merge (yb) duplicated across oth (cheap VALU).  Opart LDS-staged.
// grid(64 s-tiles, 2 o-halves, 4 n) = 512 blocks.
// ---------------------------------------------------------------------------
__global__ __launch_bounds__(512, 4)
void outproj_kernel(const float* __restrict__ x,
                    const unsigned short* __restrict__ wbf,
                    const float* __restrict__ b_out,
                    const unsigned short* __restrict__ Opart,
                    const float* __restrict__ lbuf,
                    float* __restrict__ out) {
    const int tid  = threadIdx.x;
    const int wid  = tid >> 6;         // 0..7
    const int lane = tid & 63;
    const int quad = lane >> 4;
    const int l15  = lane & 15;
    const int oh = blockIdx.y;
    const int n  = blockIdx.z;
    const int s0 = blockIdx.x * 64;
    const int swq = wid & 3;
    const int oth = wid >> 2;          // 0..1
    const int sw  = s0 + swq * 16;
    const int T  = NB * NS;

    __shared__ unsigned short Ob[4 * 64 * 128];   // 64 KB

    // stage 4 partial tiles [64 s][128 c], pre-swizzled source chunks.
    // 64 (k, seg) tasks over 8 waves; one gload16 = 1 KB = 4 rows x 256 B.
    const int lh16 = lane >> 4, lm16 = lane & 15;
#pragma unroll
    for (int j = 0; j < 8; j++) {
        int t   = j * 8 + wid;              // 0..63
        int k   = t >> 4;                   // 0..3
        int seg = t & 15;                   // 0..15
        int s   = seg * 4 + lh16;           // 0..63
        int jj  = lm16 ^ (s & 15);          // swizzled 16B chunk
        gload16(Ob + k * 8192 + seg * 512,
                Opart + ((size_t)k * T + (size_t)n * NS + s0 + s) * CI + jj * 8);
    }

    const int srow = n * NS + sw + l15;
    float l = 0.f;
#pragma unroll
    for (int k = 0; k < 4; k++) l += lbuf[k * T + srow];
    float rinv = 1.0f / l;

    __syncthreads();   // drains all gload16

    // merge from LDS: lane's row sL = swq*16 + l15, chunk g = kc*4+quad at
    // slot g ^ (sL&15)   (duplicated across the 2 o-half waves)
    const int sL = swq * 16 + l15;
    bf16x8 yb[4];
#pragma unroll
    for (int kc = 0; kc < 4; kc++) {
        float f0 = 0.f, f1 = 0.f, f2 = 0.f, f3 = 0.f;
        float f4 = 0.f, f5 = 0.f, f6 = 0.f, f7 = 0.f;
        const int slot = (kc * 4 + quad) ^ (sL & 15);
#pragma unroll
        for (int k = 0; k < 4; k++) {
            uint4 v = *(const uint4*)(Ob + k * 8192 + sL * 128 + slot * 8);
            f0 += bf2f(v.x & 0xffffu); f1 += bf2f(v.x >> 16);
            f2 += bf2f(v.y & 0xffffu); f3 += bf2f(v.y >> 16);
            f4 += bf2f(v.z & 0xffffu); f5 += bf2f(v.z >> 16);
            f6 += bf2f(v.w & 0xffffu); f7 += bf2f(v.w >> 16);
        }
        union { unsigned int uu[4]; bf16x8 vv; } r;
        r.uu[0] = pk2(f0 * rinv, f1 * rinv);
        r.uu[1] = pk2(f2 * rinv, f3 * rinv);
        r.uu[2] = pk2(f4 * rinv, f5 * rinv);
        r.uu[3] = pk2(f6 * rinv, f7 * rinv);
        yb[kc] = r.vv;
    }

    const unsigned short* wof = wbf + 98304 + (size_t)oh * 16384;
    f32x4 acc[4];
#pragma unroll
    for (int oi = 0; oi < 4; oi++) acc[oi] = (f32x4){0.f, 0.f, 0.f, 0.f};
#pragma unroll
    for (int kc = 0; kc < 4; kc++) {
#pragma unroll
        for (int oi = 0; oi < 4; oi++) {
            int ot = oth * 4 + oi;
            bf16x8 wa = *(const bf16x8*)(wof + kc * 4096 + ot * 512 + lane * 8);
            acc[oi] = MFMA16(wa, yb[kc], acc[oi]);
        }
    }
#pragma unroll
    for (int oi = 0; oi < 4; oi++) {
        int ot = oth * 4 + oi;
#pragma unroll
        for (int r = 0; r < 4; r++) {
            int o = oh * 128 + ot * 16 + quad * 4 + r;
            size_t idx = ((size_t)n * CH + o) * NS + sw + l15;
            out[idx] = x[idx] + acc[oi][r] + b_out[o];
        }
    }
}

// ---------------------------------------------------------------------------
extern "C" void kernel_launch(void* const* d_in, const int* in_sizes, int n_in,
                              void* d_out, int out_size, void* d_ws, size_t ws_size,
                              hipStream_t stream) {
    const float* x     = (const float*)d_in[0];
    const float* w_g   = (const float*)d_in[1];
    const float* b_g   = (const float*)d_in[2];
    const float* w_th  = (const float*)d_in[3];
    const float* b_th  = (const float*)d_in[4];
    const float* w_ph  = (const float*)d_in[5];
    const float* b_ph  = (const float*)d_in[6];
    const float* w_out = (const float*)d_in[7];
    const float* b_out = (const float*)d_in[8];
    float* out = (float*)d_out;

    char* ws = (char*)d_ws;
    unsigned short* theta = (unsigned short*)(ws + 0);          //  4 MiB
    unsigned short* phi   = (unsigned short*)(ws + 4194304);    //  4 MiB
    unsigned short* gT    = (unsigned short*)(ws + 8388608);    //  4 MiB
    unsigned short* Opart = (unsigned short*)(ws + 12582912);   // 16 MiB (4 splits bf16)
    float* lbuf  = (float*)(ws + 29360128);                     // 256 KiB
    unsigned short* wbf = (unsigned short*)(ws + 29622272);     // 256 KiB
    float* bsc   = (float*)(ws + 29884416);                     //  1.5 KiB

    wcvt_kernel<<<512, 256, 0, stream>>>(w_g, w_th, w_ph, w_out, b_g, b_th, b_ph, wbf, bsc);
    proj_kernel<<<dim3(64, NB), 1024, 0, stream>>>(x, wbf, bsc, theta, phi, gT);
    attn_kernel<<<dim3(16, 32), 256, 0, stream>>>(theta, phi, gT, Opart, lbuf);
    outproj_kernel<<<dim3(64, 2, NB), 512, 0, stream>>>(x, wbf, b_out, Opart, lbuf, out);
}